// Round 1
// baseline (2102.817 us; speedup 1.0000x reference)
//
#include <hip/hip_runtime.h>

namespace {
constexpr int T_ = 1024;
constexpr int NB = 256;      // batch
constexpr int TT = 40;       // timesteps per block
constexpr int NTB = (T_ + TT - 1) / TT;   // 26 time blocks

constexpr int XS_ROWS = TT + 22;   // 62  poses halo rows
constexpr int F2_ROWS = TT + 14;   // 54  feat2_in rows
constexpr int F3_ROWS = TT + 6;    // 46  feat3_in rows
constexpr int H1_ROWS = TT + 2;    // 42  h1 rows

// LDS layout (floats). Persistent region + time-multiplexed X region.
constexpr int OFF_F2IN = 0;                         // 54 x 148
constexpr int OFF_F3   = OFF_F2IN + F2_ROWS * 148;  // 7992, 46 x 52
constexpr int OFF_H1   = OFF_F3 + F3_ROWS * 52;     // 10384, 42 x 17
constexpr int OFF_B1   = OFF_H1 + H1_ROWS * 17;     // 11098, 80
constexpr int OFF_B2   = OFF_B1 + 80;               // 11178, 48
constexpr int OFF_X    = ((OFF_B2 + 48) + 3) & ~3;  // 11228 (16B aligned)
// Phase AB (stage-1 conv + A1):
constexpr int OFF_XS   = OFF_X;                     // 62 x 28
constexpr int OFF_W1S  = OFF_XS + XS_ROWS * 28;     // 2160
constexpr int OFF_A1P  = OFF_W1S + 2160;            // 5*9 x 12 = 540
// Phase C (stage-2 conv, per ci2-chunk):
constexpr int OFF_W2C  = OFF_X;                     // 48 x 76
constexpr int OFF_A2S  = OFF_W2C + 48 * 76;         // 27
// Phase DE (conv1d stack):
constexpr int OFF_WC1  = OFF_X;                     // 16 x 244
constexpr int OFF_WC2  = OFF_WC1 + 16 * 244;        // 384
constexpr int OFF_BN   = OFF_WC2 + 384;             // 48
constexpr int LDS_FLOATS = OFF_A1P + 540;           // 15664 floats = 62656 B
static_assert(LDS_FLOATS >= OFF_BN + 48, "region DE fits");
static_assert(LDS_FLOATS >= OFF_A2S + 27, "region C fits");
static_assert(LDS_FLOATS * 4 <= 64 * 1024, "under 64KB static LDS");
}

__global__ __launch_bounds__(256, 2) void aff_encoder_kernel(
    const float* __restrict__ poses, const float* __restrict__ A1,
    const float* __restrict__ A2,    const float* __restrict__ W1,
    const float* __restrict__ b1,    const float* __restrict__ W2,
    const float* __restrict__ b2,    const float* __restrict__ Wc1,
    const float* __restrict__ bc1,   const float* __restrict__ bn1w,
    const float* __restrict__ bn1b,  const float* __restrict__ bn1m,
    const float* __restrict__ bn1v,  const float* __restrict__ Wc2,
    const float* __restrict__ bc2,   const float* __restrict__ bn2w,
    const float* __restrict__ bn2b,  const float* __restrict__ bn2m,
    const float* __restrict__ bn2v,  float* __restrict__ out) {
  __shared__ __align__(16) float lds[LDS_FLOATS];
  const int tid = threadIdx.x;
  const int n = blockIdx.y;
  const int t0 = blockIdx.x * TT;

  // ---------- Phase 0: stage poses slab + stage-1 weights ----------
  for (int l = tid; l < XS_ROWS * 28; l += 256) {
    int row = l / 28, q = l - row * 28;
    int t = t0 - 11 + row;
    float v = 0.f;
    if (q < 27 && t >= 0 && t < T_) v = poses[(n * T_ + t) * 27 + q];
    lds[OFF_XS + l] = v;
  }
  for (int l = tid; l < 2160; l += 256) lds[OFF_W1S + l] = W1[l];
  for (int l = tid; l < 405; l += 256) {       // A1[k][v][w] -> padded rows of 12
    int k = l / 81, r = l - k * 81, v = r / 9, w = r - v * 9;
    lds[OFF_A1P + (k * 9 + v) * 12 + w] = A1[l];
  }
  for (int l = tid; l < 80; l += 256) lds[OFF_B1 + l] = b1[l];
  for (int l = tid; l < 48; l += 256) lds[OFF_B2 + l] = b2[l];
  __syncthreads();

  // ---------- Stage B: conv2d(W1) + A1 einsum -> feat2_in ----------
  // f2in[rt][p*48 + c*3 + e] = feat1[c][w=3p+e] at t = t0-7+rt
  for (int tau = tid; tau < F2_ROWS * 16; tau += 256) {
    const int c = tau & 15, rt2 = tau >> 4;
    const int t = t0 - 7 + rt2;
    float* f2row = lds + OFF_F2IN + rt2 * 148;
    if (t < 0 || t >= T_) {
#pragma unroll
      for (int w = 0; w < 9; ++w) f2row[(w / 3) * 48 + c * 3 + (w % 3)] = 0.f;
      continue;
    }
    float y[45];
#pragma unroll
    for (int k = 0; k < 5; ++k) {
      float bv = lds[OFF_B1 + k * 16 + c];
#pragma unroll
      for (int v = 0; v < 9; ++v) y[k * 9 + v] = bv;
    }
    for (int dh = 0; dh < 9; ++dh) {
      const float* xr = lds + OFF_XS + (rt2 + dh) * 28;
      float xv[28];
#pragma unroll
      for (int u = 0; u < 7; ++u) {
        float4 q4 = *reinterpret_cast<const float4*>(xr + u * 4);
        xv[u * 4 + 0] = q4.x; xv[u * 4 + 1] = q4.y;
        xv[u * 4 + 2] = q4.z; xv[u * 4 + 3] = q4.w;
      }
#pragma unroll
      for (int k = 0; k < 5; ++k) {
        float wk0 = lds[OFF_W1S + (k * 16 + c) * 27 + 0 * 9 + dh];
        float wk1 = lds[OFF_W1S + (k * 16 + c) * 27 + 1 * 9 + dh];
        float wk2 = lds[OFF_W1S + (k * 16 + c) * 27 + 2 * 9 + dh];
#pragma unroll
        for (int v = 0; v < 9; ++v) {
          float acc = y[k * 9 + v];
          acc = fmaf(xv[v * 3 + 0], wk0, acc);
          acc = fmaf(xv[v * 3 + 1], wk1, acc);
          acc = fmaf(xv[v * 3 + 2], wk2, acc);
          y[k * 9 + v] = acc;
        }
      }
    }
    float ft[9];
#pragma unroll
    for (int w = 0; w < 9; ++w) ft[w] = 0.f;
#pragma unroll
    for (int k = 0; k < 5; ++k)
#pragma unroll
      for (int v = 0; v < 9; ++v) {
        const float* ar = lds + OFF_A1P + (k * 9 + v) * 12;
        float4 a0 = *reinterpret_cast<const float4*>(ar);
        float4 a1 = *reinterpret_cast<const float4*>(ar + 4);
        float a8 = ar[8];
        float yv = y[k * 9 + v];
        ft[0] = fmaf(yv, a0.x, ft[0]); ft[1] = fmaf(yv, a0.y, ft[1]);
        ft[2] = fmaf(yv, a0.z, ft[2]); ft[3] = fmaf(yv, a0.w, ft[3]);
        ft[4] = fmaf(yv, a1.x, ft[4]); ft[5] = fmaf(yv, a1.y, ft[5]);
        ft[6] = fmaf(yv, a1.z, ft[6]); ft[7] = fmaf(yv, a1.w, ft[7]);
        ft[8] = fmaf(yv, a8, ft[8]);
      }
#pragma unroll
    for (int w = 0; w < 9; ++w) f2row[(w / 3) * 48 + c * 3 + (w % 3)] = ft[w];
  }
  __syncthreads();

  // ---------- Stage C: conv2d(W2) + A2 einsum -> feat3 ----------
  const int c2 = tid & 15;         // output channel-of-16
  const int rg = tid >> 4;         // row group; rows rg*3+s
  float y2a[27];                   // [s][k2][p]
#pragma unroll
  for (int s = 0; s < 3; ++s)
#pragma unroll
    for (int k2 = 0; k2 < 3; ++k2) {
      float bv = lds[OFF_B2 + k2 * 16 + c2];
#pragma unroll
      for (int p = 0; p < 3; ++p) y2a[(s * 3 + k2) * 3 + p] = bv;
    }
  for (int chunk = 0; chunk < 6; ++chunk) {
    __syncthreads();  // previous-pass reads (or stage B) done before overwrite
    for (int l = tid; l < 48 * 72; l += 256) {   // W2[o2][ci2][dh] -> [o2][dh*8+ci2l]
      int o2 = l / 72, r = l - o2 * 72;
      int ci2l = r / 9, dh = r - ci2l * 9;
      lds[OFF_W2C + o2 * 76 + dh * 8 + ci2l] =
          W2[o2 * 432 + (chunk * 8 + ci2l) * 9 + dh];
    }
    if (chunk == 0)
      for (int l = tid; l < 27; l += 256) lds[OFF_A2S + l] = A2[l];
    __syncthreads();
    for (int dh = 0; dh < 9; ++dh) {
#pragma unroll
      for (int q = 0; q < 2; ++q) {
        float4 w40 = *reinterpret_cast<const float4*>(
            lds + OFF_W2C + (0 * 16 + c2) * 76 + dh * 8 + q * 4);
        float4 w41 = *reinterpret_cast<const float4*>(
            lds + OFF_W2C + (1 * 16 + c2) * 76 + dh * 8 + q * 4);
        float4 w42 = *reinterpret_cast<const float4*>(
            lds + OFF_W2C + (2 * 16 + c2) * 76 + dh * 8 + q * 4);
#pragma unroll
        for (int s = 0; s < 3; ++s) {
          const int rt3 = rg * 3 + s;
          if (rt3 >= F3_ROWS) continue;
          const float* fr = lds + OFF_F2IN + (rt3 + dh) * 148 + chunk * 8 + q * 4;
#pragma unroll
          for (int p = 0; p < 3; ++p) {
            float4 f4 = *reinterpret_cast<const float4*>(fr + p * 48);
            float a0 = y2a[(s * 3 + 0) * 3 + p];
            float a1 = y2a[(s * 3 + 1) * 3 + p];
            float a2v = y2a[(s * 3 + 2) * 3 + p];
            a0 = fmaf(f4.x, w40.x, a0); a0 = fmaf(f4.y, w40.y, a0);
            a0 = fmaf(f4.z, w40.z, a0); a0 = fmaf(f4.w, w40.w, a0);
            a1 = fmaf(f4.x, w41.x, a1); a1 = fmaf(f4.y, w41.y, a1);
            a1 = fmaf(f4.z, w41.z, a1); a1 = fmaf(f4.w, w41.w, a1);
            a2v = fmaf(f4.x, w42.x, a2v); a2v = fmaf(f4.y, w42.y, a2v);
            a2v = fmaf(f4.z, w42.z, a2v); a2v = fmaf(f4.w, w42.w, a2v);
            y2a[(s * 3 + 0) * 3 + p] = a0;
            y2a[(s * 3 + 1) * 3 + p] = a1;
            y2a[(s * 3 + 2) * 3 + p] = a2v;
          }
        }
      }
    }
  }
  {
    float a2r[27];
#pragma unroll
    for (int i = 0; i < 27; ++i) a2r[i] = lds[OFF_A2S + i];
#pragma unroll
    for (int s = 0; s < 3; ++s) {
      const int rt3 = rg * 3 + s;
      if (rt3 < F3_ROWS) {
        const int t = t0 - 3 + rt3;
        float fw0 = 0.f, fw1 = 0.f, fw2 = 0.f;
        if (t >= 0 && t < T_) {
#pragma unroll
          for (int k2 = 0; k2 < 3; ++k2)
#pragma unroll
            for (int v = 0; v < 3; ++v) {
              float yv = y2a[(s * 3 + k2) * 3 + v];
              fw0 = fmaf(yv, a2r[k2 * 9 + v * 3 + 0], fw0);
              fw1 = fmaf(yv, a2r[k2 * 9 + v * 3 + 1], fw1);
              fw2 = fmaf(yv, a2r[k2 * 9 + v * 3 + 2], fw2);
            }
        }
        float* f3r = lds + OFF_F3 + rt3 * 52 + c2 * 3;
        f3r[0] = fw0; f3r[1] = fw1; f3r[2] = fw2;
      }
    }
  }
  __syncthreads();

  // ---------- stage conv1d weights + BN constants ----------
  for (int l = tid; l < 16 * 240; l += 256) {  // Wc1[o3][ci3][d] -> [o3][d*48+ci3]
    int o3 = l / 240, r = l - o3 * 240, ci3 = r / 5, d = r - ci3 * 5;
    lds[OFF_WC1 + o3 * 244 + d * 48 + ci3] = Wc1[l];
  }
  for (int l = tid; l < 384; l += 256) lds[OFF_WC2 + l] = Wc2[l];
  if (tid < 16) {
    float s1 = bn1w[tid] * rsqrtf(bn1v[tid] + 1e-5f);
    lds[OFF_BN + tid] = s1;
    lds[OFF_BN + 16 + tid] = bc1[tid] * s1 + bn1b[tid] - bn1m[tid] * s1;
  } else if (tid < 24) {
    int i = tid - 16;
    float s2 = bn2w[i] * rsqrtf(bn2v[i] + 1e-5f);
    lds[OFF_BN + 32 + i] = s2;
    lds[OFF_BN + 40 + i] = bc2[i] * s2 + bn2b[i] - bn2m[i] * s2;
  }
  __syncthreads();

  // ---------- Stage D: conv1d(Wc1,5) + BN + leaky -> h1 ----------
  for (int tau = tid; tau < H1_ROWS * 16; tau += 256) {
    const int o3 = tau & 15, rh = tau >> 4;
    const int t = t0 - 1 + rh;
    float val = 0.f;
    if (t >= 0 && t < T_) {
      float acc = 0.f;
      for (int d = 0; d < 5; ++d) {
        const float* fr = lds + OFF_F3 + (rh + d) * 52;
        const float* wr = lds + OFF_WC1 + o3 * 244 + d * 48;
#pragma unroll
        for (int q = 0; q < 12; ++q) {
          float4 f4 = *reinterpret_cast<const float4*>(fr + q * 4);
          float4 w4 = *reinterpret_cast<const float4*>(wr + q * 4);
          acc = fmaf(f4.x, w4.x, acc); acc = fmaf(f4.y, w4.y, acc);
          acc = fmaf(f4.z, w4.z, acc); acc = fmaf(f4.w, w4.w, acc);
        }
      }
      float v2 = acc * lds[OFF_BN + o3] + lds[OFF_BN + 16 + o3];
      val = v2 > 0.f ? v2 : 0.01f * v2;
    }
    lds[OFF_H1 + rh * 17 + o3] = val;
  }
  __syncthreads();

  // ---------- Stage E: conv1d(Wc2,3) + BN + leaky -> out (n,t,8) ----------
  for (int tau = tid; tau < TT * 8; tau += 256) {
    const int o4 = tau & 7, rt = tau >> 3;
    const int t = t0 + rt;
    if (t >= T_) continue;
    float acc = 0.f;
#pragma unroll
    for (int d = 0; d < 3; ++d) {
      const float* hr = lds + OFF_H1 + (rt + d) * 17;
      const float* wr = lds + OFF_WC2 + o4 * 48;
#pragma unroll
      for (int ci4 = 0; ci4 < 16; ++ci4)
        acc = fmaf(hr[ci4], wr[ci4 * 3 + d], acc);
    }
    float v2 = acc * lds[OFF_BN + 32 + o4] + lds[OFF_BN + 40 + o4];
    out[((long)n * T_ + t) * 8 + o4] = v2 > 0.f ? v2 : 0.01f * v2;
  }
}

extern "C" void kernel_launch(void* const* d_in, const int* in_sizes, int n_in,
                              void* d_out, int out_size, void* d_ws, size_t ws_size,
                              hipStream_t stream) {
  (void)in_sizes; (void)n_in; (void)d_ws; (void)ws_size; (void)out_size;
  const float* poses = (const float*)d_in[0];
  const float* A1    = (const float*)d_in[1];
  const float* A2    = (const float*)d_in[2];
  const float* W1    = (const float*)d_in[3];
  const float* b1    = (const float*)d_in[4];
  const float* W2    = (const float*)d_in[5];
  const float* b2    = (const float*)d_in[6];
  const float* Wc1   = (const float*)d_in[7];
  const float* bc1   = (const float*)d_in[8];
  const float* bn1w  = (const float*)d_in[9];
  const float* bn1b  = (const float*)d_in[10];
  const float* bn1m  = (const float*)d_in[11];
  const float* bn1v  = (const float*)d_in[12];
  const float* Wc2   = (const float*)d_in[13];
  const float* bc2   = (const float*)d_in[14];
  const float* bn2w  = (const float*)d_in[15];
  const float* bn2b  = (const float*)d_in[16];
  const float* bn2m  = (const float*)d_in[17];
  const float* bn2v  = (const float*)d_in[18];
  float* out = (float*)d_out;

  dim3 grid(NTB, NB);
  dim3 block(256);
  hipLaunchKernelGGL(aff_encoder_kernel, grid, block, 0, stream,
                     poses, A1, A2, W1, b1, W2, b2, Wc1, bc1,
                     bn1w, bn1b, bn1m, bn1v, Wc2, bc2, bn2w, bn2b, bn2m, bn2v,
                     out);
}

// Round 2
// 468.689 us; speedup vs baseline: 4.4866x; 4.4866x over previous
//
#include <hip/hip_runtime.h>

namespace {
constexpr int T_ = 1024;
constexpr int NBATCH = 256;
constexpr int TT = 50;
constexpr int NTB = 21;               // ceil(1024/50)

// ---- d_ws layout (bytes) ----
constexpr int WFB_OFF = 0;            // 144 x 256 bf16 (stage1+A1 fused, B^T)
constexpr int WFC_OFF = 73728;        // 48 x 1312 bf16 (stage2+A2 fused, B^T)
constexpr int WFD_OFF = 199680;       // 16 x 256 bf16 (conv1d_1 * bn-scale, B^T)
constexpr int BIASB_OFF = 207872;     // 144 f32
constexpr int BIASC_OFF = 208448;     // 48 f32
constexpr int BIASD_OFF = 208640;     // 16 f32
constexpr int WS_BYTES = 208704;

// ---- LDS layout (bytes). xim dies after GEMM-B; f3/h1 overlay it. ----
constexpr int XIM_OFF = 0;            // 80 rows x 528 (264 bf16/row, 243 used)
constexpr int F3_OFF = 0;             // 70 rows x 112 (56 bf16/row, 48 used)
constexpr int H1_OFF = 7840;          // 52 rows x 68  (17 f32/row, 16 used)
constexpr int F2IN_OFF = 42240;       // 74 rows x 304 (152 bf16/row, 144 used)
constexpr int SMEM_BYTES = F2IN_OFF + 74 * 304;   // 64736 <= 64KB
static_assert(SMEM_BYTES <= 65536, "LDS");

typedef __attribute__((ext_vector_type(8))) short short8v;
typedef __attribute__((ext_vector_type(4))) float f32x4;

__device__ inline unsigned short f2b(float f) {
  union { float f; unsigned u; } v; v.f = f;
  unsigned r = (v.u + 0x7FFFu + ((v.u >> 16) & 1u)) >> 16;
  return (unsigned short)r;
}
}

// ================= prep: fold einsums/BN into conv weight tables ===========
__global__ void prep_kernel(const float* __restrict__ A1, const float* __restrict__ A2,
                            const float* __restrict__ W1, const float* __restrict__ b1,
                            const float* __restrict__ W2, const float* __restrict__ b2,
                            const float* __restrict__ Wc1, const float* __restrict__ bc1,
                            const float* __restrict__ bn1w, const float* __restrict__ bn1b,
                            const float* __restrict__ bn1m, const float* __restrict__ bn1v,
                            unsigned char* __restrict__ ws) {
  unsigned short* wfB = (unsigned short*)(ws + WFB_OFF);
  unsigned short* wfC = (unsigned short*)(ws + WFC_OFF);
  unsigned short* wfD = (unsigned short*)(ws + WFD_OFF);
  float* biasB = (float*)(ws + BIASB_OFF);
  float* biasC = (float*)(ws + BIASC_OFF);
  float* biasD = (float*)(ws + BIASD_OFF);
  const int total = 36864 + 62976 + 4096 + 208;
  for (int idx = blockIdx.x * 256 + threadIdx.x; idx < total; idx += gridDim.x * 256) {
    if (idx < 36864) {                      // wfB[ncol][k], k = dh*27 + v*3 + ci
      int ncol = idx >> 8, k = idx & 255;
      float val = 0.f;
      if (k < 243) {
        int dh = k / 27, m = k - dh * 27, v = m / 3, ci = m - v * 3;
        int p = ncol / 48, rr = ncol - p * 48, c = rr / 3, e = rr - c * 3;
        int w = p * 3 + e;
        for (int k5 = 0; k5 < 5; ++k5)
          val += W1[(k5 * 16 + c) * 27 + ci * 9 + dh] * A1[k5 * 81 + v * 9 + w];
      }
      wfB[idx] = f2b(val);
    } else if (idx < 36864 + 62976) {       // wfC[nc][k], k = dh*144 + p*48 + ci2
      int i2 = idx - 36864;
      int nc = i2 / 1312, k = i2 - nc * 1312;
      float val = 0.f;
      if (k < 1296) {
        int dh = k / 144, rr = k - dh * 144, p = rr / 48, ci2 = rr - p * 48;
        int c2 = nc / 3, w2 = nc - c2 * 3;
        for (int k2 = 0; k2 < 3; ++k2)
          val += W2[(k2 * 16 + c2) * 432 + ci2 * 9 + dh] * A2[k2 * 9 + p * 3 + w2];
      }
      wfC[i2] = f2b(val);
    } else if (idx < 36864 + 62976 + 4096) {  // wfD[o3][k], k = d*48 + ci
      int i3 = idx - 99840;
      int o3 = i3 >> 8, k = i3 & 255;
      float val = 0.f;
      if (k < 240) {
        int d = k / 48, ci = k - d * 48;
        float s1 = bn1w[o3] * rsqrtf(bn1v[o3] + 1e-5f);
        val = Wc1[o3 * 240 + ci * 5 + d] * s1;
      }
      wfD[i3] = f2b(val);
    } else {
      int ib = idx - 103936;
      if (ib < 144) {
        int p = ib / 48, rr = ib - p * 48, c = rr / 3, e = rr - c * 3;
        int w = p * 3 + e;
        float val = 0.f;
        for (int k5 = 0; k5 < 5; ++k5)
          for (int v = 0; v < 9; ++v)
            val += b1[k5 * 16 + c] * A1[k5 * 81 + v * 9 + w];
        biasB[ib] = val;
      } else if (ib < 192) {
        int nc = ib - 144, c2 = nc / 3, w2 = nc - c2 * 3;
        float val = 0.f;
        for (int k2 = 0; k2 < 3; ++k2)
          for (int p = 0; p < 3; ++p)
            val += b2[k2 * 16 + c2] * A2[k2 * 9 + p * 3 + w2];
        biasC[nc] = val;
      } else {
        int o3 = ib - 192;
        float s1 = bn1w[o3] * rsqrtf(bn1v[o3] + 1e-5f);
        biasD[o3] = bc1[o3] * s1 + bn1b[o3] - bn1m[o3] * s1;
      }
    }
  }
}

// ================= main fused kernel =======================================
__global__ __launch_bounds__(256, 2) void aff_encoder_kernel(
    const float* __restrict__ poses,
    const float* __restrict__ Wc2, const float* __restrict__ bc2,
    const float* __restrict__ bn2w, const float* __restrict__ bn2b,
    const float* __restrict__ bn2m, const float* __restrict__ bn2v,
    const unsigned char* __restrict__ ws, float* __restrict__ out) {
  __shared__ __attribute__((aligned(16))) unsigned char smem[SMEM_BYTES];
  const unsigned short* wfB = (const unsigned short*)(ws + WFB_OFF);
  const unsigned short* wfC = (const unsigned short*)(ws + WFC_OFF);
  const unsigned short* wfD = (const unsigned short*)(ws + WFD_OFF);
  const float* biasB = (const float*)(ws + BIASB_OFF);
  const float* biasC = (const float*)(ws + BIASC_OFF);
  const float* biasD = (const float*)(ws + BIASD_OFF);

  const int tid = threadIdx.x;
  const int n = blockIdx.y;
  const int t0 = blockIdx.x * TT;
  const int w = tid >> 6;          // wave id 0..3
  const int l = tid & 63;          // lane
  const int lrow = l & 15;
  const int q = l >> 4;
  const int q8 = q * 8;

  // ---- Phase 1: build xim (im2col = row-concat of poses rows, bf16) ----
  // xim[r][dh*27 + m] = poses[n][t0-11+r+dh][m]; rows r<80 (72 real + pad)
  for (int it = tid; it < 720; it += 256) {
    int r = it / 9, dh = it - r * 9;
    int tg = t0 - 11 + r + dh;
    unsigned char* dst = smem + XIM_OFF + r * 528 + dh * 54;
    if (tg >= 0 && tg < T_) {
      const float* src = poses + ((long)n * T_ + tg) * 27;
      for (int m = 0; m < 27; ++m) *(unsigned short*)(dst + m * 2) = f2b(src[m]);
    } else {
      for (int m = 0; m < 27; ++m) *(unsigned short*)(dst + m * 2) = 0;
    }
  }
  for (int it = tid; it < 80 * 21; it += 256) {   // zero K-pad cols 243..263
    int r = it / 21, m2 = 243 + (it - r * 21);
    *(unsigned short*)(smem + XIM_OFF + r * 528 + m2 * 2) = 0;
  }
  for (int it = tid; it < 304; it += 256) {       // zero f2in pad rows 72,73
    int rr = 72 + it / 152, cc = it - (it / 152) * 152;
    *(unsigned short*)(smem + F2IN_OFF + rr * 304 + cc * 2) = 0;
  }
  __syncthreads();

  // ---- GEMM B: (stage1 conv + A1 einsum) fused. M=80(72 real), N=144, K=256 ----
  for (int pi = w; pi < 45; pi += 4) {
    const int mt = pi / 9, nt = pi - mt * 9;
    const unsigned abase = XIM_OFF + (mt * 16 + lrow) * 528 + q8 * 2;
    const unsigned short* bptr = wfB + ((nt * 16 + lrow) << 8) + q8;
    f32x4 acc = {0.f, 0.f, 0.f, 0.f};
#pragma unroll
    for (int kk = 0; kk < 8; ++kk) {
      short8v a = *(const short8v*)(smem + abase + kk * 64);
      short8v b = *(const short8v*)(bptr + kk * 32);
      acc = __builtin_amdgcn_mfma_f32_16x16x32_bf16(a, b, acc, 0, 0, 0);
    }
    const int ncol = nt * 16 + lrow;
    const float bias = biasB[ncol];
#pragma unroll
    for (int j = 0; j < 4; ++j) {
      int r = mt * 16 + q * 4 + j;
      if (r < 72) {
        int t = t0 - 7 + r;
        float v = (t >= 0 && t < T_) ? acc[j] + bias : 0.f;
        *(unsigned short*)(smem + F2IN_OFF + r * 304 + ncol * 2) = f2b(v);
      }
    }
  }
  __syncthreads();

  // ---- zero f3 pad (disjoint from GEMM-C epilogue writes) ----
  for (int it = tid; it < 560; it += 256) {       // cols 48..55, rows 0..69
    int rr = it >> 3, cc = 48 + (it & 7);
    *(unsigned short*)(smem + F3_OFF + rr * 112 + cc * 2) = 0;
  }
  for (int it = tid; it < 672; it += 256) {       // rows 56..69, cols 0..47
    int rr = 56 + it / 48, cc = it - (it / 48) * 48;
    *(unsigned short*)(smem + F3_OFF + rr * 112 + cc * 2) = 0;
  }

  // ---- GEMM C: (stage2 conv + A2 einsum) fused. M=64(56 real), N=48, K=1312 ----
  for (int pi = w; pi < 12; pi += 4) {
    const int mt = pi / 3, nt = pi - mt * 3;
    const int arowbase = mt * 16 + lrow;
    const unsigned short* bptr = wfC + (nt * 16 + lrow) * 1312 + q8;
    f32x4 acc = {0.f, 0.f, 0.f, 0.f};
    int dh = 0, rem = q8;                          // k8 = kk*32 + q8
    for (int kk = 0; kk < 41; ++kk) {
      short8v a = *(const short8v*)(smem + F2IN_OFF + (arowbase + dh) * 304 + rem * 2);
      short8v b = *(const short8v*)(bptr + kk * 32);
      acc = __builtin_amdgcn_mfma_f32_16x16x32_bf16(a, b, acc, 0, 0, 0);
      rem += 32;
      int ge = rem >= 144;
      rem -= ge ? 144 : 0;
      dh += ge;
    }
    const int ncol2 = nt * 16 + lrow;
    const float bias = biasC[ncol2];
#pragma unroll
    for (int j = 0; j < 4; ++j) {
      int rt3 = mt * 16 + q * 4 + j;
      if (rt3 < 56) {
        int t = t0 - 3 + rt3;
        float v = (t >= 0 && t < T_) ? acc[j] + bias : 0.f;
        *(unsigned short*)(smem + F3_OFF + rt3 * 112 + ncol2 * 2) = f2b(v);
      }
    }
  }
  __syncthreads();

  // ---- GEMM D: conv1d(5) + BN + leaky. M=64(52 real), N=16, K=256 ----
  {
    const int mt = w;
    const int arowbase = mt * 16 + lrow;
    const unsigned short* bptr = wfD + (lrow << 8) + q8;
    f32x4 acc = {0.f, 0.f, 0.f, 0.f};
    int d = 0, rem = q8;
#pragma unroll
    for (int kk = 0; kk < 8; ++kk) {
      short8v a = *(const short8v*)(smem + F3_OFF + (arowbase + d) * 112 + rem * 2);
      short8v b = *(const short8v*)(bptr + kk * 32);
      acc = __builtin_amdgcn_mfma_f32_16x16x32_bf16(a, b, acc, 0, 0, 0);
      rem += 32;
      int ge = rem >= 48;
      rem -= ge ? 48 : 0;
      d += ge;
    }
    const float bias = biasD[lrow];
#pragma unroll
    for (int j = 0; j < 4; ++j) {
      int rh = mt * 16 + q * 4 + j;
      if (rh < 52) {
        int t = t0 - 1 + rh;
        float v = 0.f;
        if (t >= 0 && t < T_) {
          float x = acc[j] + bias;
          v = x > 0.f ? x : 0.01f * x;
        }
        *(float*)(smem + H1_OFF + (rh * 17 + lrow) * 4) = v;
      }
    }
  }
  __syncthreads();

  // ---- Stage E: conv1d(3) + BN + leaky -> out[n][t][8] (VALU, tiny) ----
  for (int it = tid; it < TT * 8; it += 256) {
    int rt = it >> 3, o4 = it & 7;
    int t = t0 + rt;
    if (t >= T_) continue;
    float s2 = bn2w[o4] * rsqrtf(bn2v[o4] + 1e-5f);
    float t2 = bc2[o4] * s2 + bn2b[o4] - bn2m[o4] * s2;
    float acc = 0.f;
#pragma unroll
    for (int d = 0; d < 3; ++d) {
      const float* hr = (const float*)(smem + H1_OFF + (rt + d) * 68);
#pragma unroll
      for (int ci = 0; ci < 16; ++ci)
        acc = fmaf(hr[ci], Wc2[(o4 * 16 + ci) * 3 + d], acc);
    }
    float v = acc * s2 + t2;
    out[((long)n * T_ + t) * 8 + o4] = v > 0.f ? v : 0.01f * v;
  }
}

extern "C" void kernel_launch(void* const* d_in, const int* in_sizes, int n_in,
                              void* d_out, int out_size, void* d_ws, size_t ws_size,
                              hipStream_t stream) {
  (void)in_sizes; (void)n_in; (void)out_size; (void)ws_size;
  const float* poses = (const float*)d_in[0];
  const float* A1    = (const float*)d_in[1];
  const float* A2    = (const float*)d_in[2];
  const float* W1    = (const float*)d_in[3];
  const float* b1    = (const float*)d_in[4];
  const float* W2    = (const float*)d_in[5];
  const float* b2    = (const float*)d_in[6];
  const float* Wc1   = (const float*)d_in[7];
  const float* bc1   = (const float*)d_in[8];
  const float* bn1w  = (const float*)d_in[9];
  const float* bn1b  = (const float*)d_in[10];
  const float* bn1m  = (const float*)d_in[11];
  const float* bn1v  = (const float*)d_in[12];
  const float* Wc2   = (const float*)d_in[13];
  const float* bc2   = (const float*)d_in[14];
  const float* bn2w  = (const float*)d_in[15];
  const float* bn2b  = (const float*)d_in[16];
  const float* bn2m  = (const float*)d_in[17];
  const float* bn2v  = (const float*)d_in[18];
  float* out = (float*)d_out;
  unsigned char* ws = (unsigned char*)d_ws;

  hipLaunchKernelGGL(prep_kernel, dim3(128), dim3(256), 0, stream,
                     A1, A2, W1, b1, W2, b2, Wc1, bc1, bn1w, bn1b, bn1m, bn1v, ws);
  hipLaunchKernelGGL(aff_encoder_kernel, dim3(NTB, NBATCH), dim3(256), 0, stream,
                     poses, Wc2, bc2, bn2w, bn2b, bn2m, bn2v, ws, out);
}

// Round 3
// 365.453 us; speedup vs baseline: 5.7540x; 1.2825x over previous
//
#include <hip/hip_runtime.h>

namespace {
constexpr int T_ = 1024;
constexpr int NBATCH = 256;
constexpr int TT = 50;
constexpr int NTB = 21;               // ceil(1024/50)

// ---- d_ws layout (bytes) ----
constexpr int WFB_OFF = 0;            // 144 x 288 bf16 (stage1+A1 fused, dh-major K, B^T)
constexpr int WFC_OFF = 82944;        // 48 x 1312 bf16 (stage2+A2 fused, B^T)
constexpr int WFD_OFF = 208896;       // 16 x 256 bf16 (conv1d_1 * bn-scale, B^T)
constexpr int BIASB_OFF = 217088;     // 144 f32
constexpr int BIASC_OFF = 217664;     // 48 f32
constexpr int BIASD_OFF = 217856;     // 16 f32

// ---- LDS layout (bytes) ----
constexpr int F2IN_OFF = 0;                      // 73 rows x 304 (152 bf16, 144 used)
constexpr int F3_OFF   = F2IN_OFF + 73 * 304;    // 22192: 70 rows x 112 (56 bf16, 48 used)
constexpr int SLAB_OFF = F3_OFF + 70 * 112;      // 30032: 88 rows x 80 (40 bf16, 27 used)
constexpr int H1_OFF   = SLAB_OFF;               // overlay: 52 rows x 68 (17 f32, 16 used)
constexpr int SMEM_BYTES = SLAB_OFF + 88 * 80;   // 37072 -> 4 blocks/CU
static_assert(SMEM_BYTES <= 40448, "4 blocks/CU");

typedef __attribute__((ext_vector_type(8))) short short8v;
typedef __attribute__((ext_vector_type(4))) float f32x4;

__device__ inline unsigned short f2b(float f) {
  union { float f; unsigned u; } v; v.f = f;
  unsigned r = (v.u + 0x7FFFu + ((v.u >> 16) & 1u)) >> 16;
  return (unsigned short)r;
}
}

// ================= prep: fold einsums/BN into conv weight tables ===========
__global__ void prep_kernel(const float* __restrict__ A1, const float* __restrict__ A2,
                            const float* __restrict__ W1, const float* __restrict__ b1,
                            const float* __restrict__ W2, const float* __restrict__ b2,
                            const float* __restrict__ Wc1, const float* __restrict__ bc1,
                            const float* __restrict__ bn1w, const float* __restrict__ bn1b,
                            const float* __restrict__ bn1m, const float* __restrict__ bn1v,
                            unsigned char* __restrict__ ws) {
  unsigned short* wfB = (unsigned short*)(ws + WFB_OFF);
  unsigned short* wfC = (unsigned short*)(ws + WFC_OFF);
  unsigned short* wfD = (unsigned short*)(ws + WFD_OFF);
  float* biasB = (float*)(ws + BIASB_OFF);
  float* biasC = (float*)(ws + BIASC_OFF);
  float* biasD = (float*)(ws + BIASD_OFF);
  const int NWFB = 144 * 288;                       // 41472
  const int total = NWFB + 62976 + 4096 + 208;
  for (int idx = blockIdx.x * 256 + threadIdx.x; idx < total; idx += gridDim.x * 256) {
    if (idx < NWFB) {                      // wfB[ncol][dh*32 + mm], mm = v*3+ci
      int ncol = idx / 288, k = idx - ncol * 288;
      int dh = k >> 5, mm = k & 31;
      float val = 0.f;
      if (mm < 27) {
        int v = mm / 3, ci = mm - v * 3;
        int p = ncol / 48, rr = ncol - p * 48, c = rr / 3, e = rr - c * 3;
        int w = p * 3 + e;
        for (int k5 = 0; k5 < 5; ++k5)
          val += W1[(k5 * 16 + c) * 27 + ci * 9 + dh] * A1[k5 * 81 + v * 9 + w];
      }
      wfB[idx] = f2b(val);
    } else if (idx < NWFB + 62976) {       // wfC[nc][k], k = dh*144 + p*48 + ci2
      int i2 = idx - NWFB;
      int nc = i2 / 1312, k = i2 - nc * 1312;
      float val = 0.f;
      if (k < 1296) {
        int dh = k / 144, rr = k - dh * 144, p = rr / 48, ci2 = rr - p * 48;
        int c2 = nc / 3, w2 = nc - c2 * 3;
        for (int k2 = 0; k2 < 3; ++k2)
          val += W2[(k2 * 16 + c2) * 432 + ci2 * 9 + dh] * A2[k2 * 9 + p * 3 + w2];
      }
      wfC[i2] = f2b(val);
    } else if (idx < NWFB + 62976 + 4096) {  // wfD[o3][k], k = d*48 + ci
      int i3 = idx - (NWFB + 62976);
      int o3 = i3 >> 8, k = i3 & 255;
      float val = 0.f;
      if (k < 240) {
        int d = k / 48, ci = k - d * 48;
        float s1 = bn1w[o3] * rsqrtf(bn1v[o3] + 1e-5f);
        val = Wc1[o3 * 240 + ci * 5 + d] * s1;
      }
      wfD[i3] = f2b(val);
    } else {
      int ib = idx - (NWFB + 62976 + 4096);
      if (ib < 144) {
        int p = ib / 48, rr = ib - p * 48, c = rr / 3, e = rr - c * 3;
        int w = p * 3 + e;
        float val = 0.f;
        for (int k5 = 0; k5 < 5; ++k5)
          for (int v = 0; v < 9; ++v)
            val += b1[k5 * 16 + c] * A1[k5 * 81 + v * 9 + w];
        biasB[ib] = val;
      } else if (ib < 192) {
        int nc = ib - 144, c2 = nc / 3, w2 = nc - c2 * 3;
        float val = 0.f;
        for (int k2 = 0; k2 < 3; ++k2)
          for (int p = 0; p < 3; ++p)
            val += b2[k2 * 16 + c2] * A2[k2 * 9 + p * 3 + w2];
        biasC[nc] = val;
      } else {
        int o3 = ib - 192;
        float s1 = bn1w[o3] * rsqrtf(bn1v[o3] + 1e-5f);
        biasD[o3] = bc1[o3] * s1 + bn1b[o3] - bn1m[o3] * s1;
      }
    }
  }
}

// ================= main fused kernel =======================================
__global__ __launch_bounds__(256, 4) void aff_encoder_kernel(
    const float* __restrict__ poses,
    const float* __restrict__ Wc2, const float* __restrict__ bc2,
    const float* __restrict__ bn2w, const float* __restrict__ bn2b,
    const float* __restrict__ bn2m, const float* __restrict__ bn2v,
    const unsigned char* __restrict__ ws, float* __restrict__ out) {
  __shared__ __attribute__((aligned(16))) unsigned char smem[SMEM_BYTES];
  const unsigned short* wfB = (const unsigned short*)(ws + WFB_OFF);
  const unsigned short* wfC = (const unsigned short*)(ws + WFC_OFF);
  const unsigned short* wfD = (const unsigned short*)(ws + WFD_OFF);
  const float* biasB = (const float*)(ws + BIASB_OFF);
  const float* biasC = (const float*)(ws + BIASC_OFF);
  const float* biasD = (const float*)(ws + BIASD_OFF);

  const int tid = threadIdx.x;
  const int n = blockIdx.y;
  const int t0 = blockIdx.x * TT;
  const int w = tid >> 6;          // wave id 0..3
  const int l = tid & 63;          // lane
  const int lrow = l & 15;
  const int q = l >> 4;
  const int q8 = q * 8;

  // ---- Phase 1: stage pose slab (bf16) + zero pads ----
  // slab[r][m] = poses[n][t0-11+r][m], 88 rows x 40 (m<27 real)
  {
    unsigned short* slab = (unsigned short*)(smem + SLAB_OFF);
    for (int it = tid; it < 88 * 40; it += 256) {
      int r = it / 40, m = it - r * 40;
      int t = t0 - 11 + r;
      float v = 0.f;
      if (m < 27 && t >= 0 && t < T_) v = poses[((long)n * T_ + t) * 27 + m];
      slab[it] = f2b(v);
    }
    // zero f3 rows 56..68 (read by GEMM-D halo/K-pad, never written by GEMM C)
    for (int it = tid; it < 13 * 48; it += 256) {
      int rr = 56 + it / 48, cc = it - (it / 48) * 48;
      *(unsigned short*)(smem + F3_OFF + rr * 112 + cc * 2) = 0;
    }
    // zero f2in pad row 72 (read by GEMM-C K-pad tail)
    for (int it = tid; it < 152; it += 256)
      *(unsigned short*)(smem + F2IN_OFF + 72 * 304 + it * 2) = 0;
  }
  __syncthreads();

  // ---- GEMM B: (stage1 conv + A1) as 9 shifted K=32 GEMMs. M=80(72), N=144 ----
  for (int pi = w; pi < 45; pi += 4) {
    const int mt = pi / 9, nt = pi - mt * 9;
    const unsigned abase = SLAB_OFF + ((mt * 16 + lrow) * 40 + q8) * 2;
    const unsigned short* bptr = wfB + (nt * 16 + lrow) * 288 + q8;
    f32x4 acc0 = {0.f, 0.f, 0.f, 0.f}, acc1 = {0.f, 0.f, 0.f, 0.f};
#pragma unroll
    for (int dh = 0; dh < 9; ++dh) {
      short8v a = *(const short8v*)(smem + abase + dh * 80);
      short8v b = *(const short8v*)(bptr + dh * 32);
      if (dh & 1) acc1 = __builtin_amdgcn_mfma_f32_16x16x32_bf16(a, b, acc1, 0, 0, 0);
      else        acc0 = __builtin_amdgcn_mfma_f32_16x16x32_bf16(a, b, acc0, 0, 0, 0);
    }
    const int ncol = nt * 16 + lrow;
    const float bias = biasB[ncol];
#pragma unroll
    for (int j = 0; j < 4; ++j) {
      int r = mt * 16 + q * 4 + j;
      if (r < 72) {
        int t = t0 - 7 + r;
        float v = (t >= 0 && t < T_) ? acc0[j] + acc1[j] + bias : 0.f;
        *(unsigned short*)(smem + F2IN_OFF + r * 304 + ncol * 2) = f2b(v);
      }
    }
  }
  __syncthreads();

  // ---- GEMM C: (stage2 conv + A2) fused. M=64(56 real), N=48, K=1312 ----
  for (int pi = w; pi < 12; pi += 4) {
    const int mt = pi / 3, nt = pi - mt * 3;
    const int arowbase = mt * 16 + lrow;
    const unsigned short* bptr = wfC + (nt * 16 + lrow) * 1312 + q8;
    f32x4 acc0 = {0.f, 0.f, 0.f, 0.f}, acc1 = {0.f, 0.f, 0.f, 0.f};
    int dh = 0, rem = q8;                          // k = kk*32 + q8
    for (int kk = 0; kk < 41; ++kk) {
      short8v a = *(const short8v*)(smem + F2IN_OFF + (arowbase + dh) * 304 + rem * 2);
      short8v b = *(const short8v*)(bptr + kk * 32);
      if (kk & 1) acc1 = __builtin_amdgcn_mfma_f32_16x16x32_bf16(a, b, acc1, 0, 0, 0);
      else        acc0 = __builtin_amdgcn_mfma_f32_16x16x32_bf16(a, b, acc0, 0, 0, 0);
      rem += 32;
      int ge = rem >= 144;
      rem -= ge ? 144 : 0;
      dh += ge;
    }
    const int ncol2 = nt * 16 + lrow;
    const float bias = biasC[ncol2];
#pragma unroll
    for (int j = 0; j < 4; ++j) {
      int rt3 = mt * 16 + q * 4 + j;
      if (rt3 < 56) {
        int t = t0 - 3 + rt3;
        float v = (t >= 0 && t < T_) ? acc0[j] + acc1[j] + bias : 0.f;
        *(unsigned short*)(smem + F3_OFF + rt3 * 112 + ncol2 * 2) = f2b(v);
      }
    }
  }
  __syncthreads();

  // ---- GEMM D: conv1d(5) + BN + leaky. M=64(52 real), N=16, K=256 ----
  {
    const int mt = w;
    const int arowbase = mt * 16 + lrow;
    const unsigned short* bptr = wfD + (lrow << 8) + q8;
    f32x4 acc0 = {0.f, 0.f, 0.f, 0.f}, acc1 = {0.f, 0.f, 0.f, 0.f};
    int d = 0, rem = q8;
#pragma unroll
    for (int kk = 0; kk < 8; ++kk) {
      short8v a = *(const short8v*)(smem + F3_OFF + (arowbase + d) * 112 + rem * 2);
      short8v b = *(const short8v*)(bptr + kk * 32);
      if (kk & 1) acc1 = __builtin_amdgcn_mfma_f32_16x16x32_bf16(a, b, acc1, 0, 0, 0);
      else        acc0 = __builtin_amdgcn_mfma_f32_16x16x32_bf16(a, b, acc0, 0, 0, 0);
      rem += 32;
      int ge = rem >= 48;
      rem -= ge ? 48 : 0;
      d += ge;
    }
    const float bias = biasD[lrow];
#pragma unroll
    for (int j = 0; j < 4; ++j) {
      int rh = mt * 16 + q * 4 + j;
      if (rh < 52) {
        int t = t0 - 1 + rh;
        float v = 0.f;
        if (t >= 0 && t < T_) {
          float x = acc0[j] + acc1[j] + bias;
          v = x > 0.f ? x : 0.01f * x;
        }
        *(float*)(smem + H1_OFF + (rh * 17 + lrow) * 4) = v;
      }
    }
  }
  __syncthreads();

  // ---- Stage E: conv1d(3) + BN + leaky -> out[n][t][8] ----
  for (int it = tid; it < TT * 8; it += 256) {
    int rt = it >> 3, o4 = it & 7;
    int t = t0 + rt;
    if (t >= T_) continue;
    float s2 = bn2w[o4] * rsqrtf(bn2v[o4] + 1e-5f);
    float t2 = bc2[o4] * s2 + bn2b[o4] - bn2m[o4] * s2;
    float acc = 0.f;
#pragma unroll
    for (int d = 0; d < 3; ++d) {
      const float* hr = (const float*)(smem + H1_OFF + (rt + d) * 68);
#pragma unroll
      for (int ci = 0; ci < 16; ++ci)
        acc = fmaf(hr[ci], Wc2[(o4 * 16 + ci) * 3 + d], acc);
    }
    float v = acc * s2 + t2;
    out[((long)n * T_ + t) * 8 + o4] = v > 0.f ? v : 0.01f * v;
  }
}

extern "C" void kernel_launch(void* const* d_in, const int* in_sizes, int n_in,
                              void* d_out, int out_size, void* d_ws, size_t ws_size,
                              hipStream_t stream) {
  (void)in_sizes; (void)n_in; (void)out_size; (void)ws_size;
  const float* poses = (const float*)d_in[0];
  const float* A1    = (const float*)d_in[1];
  const float* A2    = (const float*)d_in[2];
  const float* W1    = (const float*)d_in[3];
  const float* b1    = (const float*)d_in[4];
  const float* W2    = (const float*)d_in[5];
  const float* b2    = (const float*)d_in[6];
  const float* Wc1   = (const float*)d_in[7];
  const float* bc1   = (const float*)d_in[8];
  const float* bn1w  = (const float*)d_in[9];
  const float* bn1b  = (const float*)d_in[10];
  const float* bn1m  = (const float*)d_in[11];
  const float* bn1v  = (const float*)d_in[12];
  const float* Wc2   = (const float*)d_in[13];
  const float* bc2   = (const float*)d_in[14];
  const float* bn2w  = (const float*)d_in[15];
  const float* bn2b  = (const float*)d_in[16];
  const float* bn2m  = (const float*)d_in[17];
  const float* bn2v  = (const float*)d_in[18];
  float* out = (float*)d_out;
  unsigned char* ws = (unsigned char*)d_ws;

  hipLaunchKernelGGL(prep_kernel, dim3(128), dim3(256), 0, stream,
                     A1, A2, W1, b1, W2, b2, Wc1, bc1, bn1w, bn1b, bn1m, bn1v, ws);
  hipLaunchKernelGGL(aff_encoder_kernel, dim3(NTB, NBATCH), dim3(256), 0, stream,
                     poses, Wc2, bc2, bn2w, bn2b, bn2m, bn2v, ws, out);
}

// Round 4
// 339.445 us; speedup vs baseline: 6.1949x; 1.0766x over previous
//
#include <hip/hip_runtime.h>

namespace {
constexpr int T_ = 1024;
constexpr int NBATCH = 256;
constexpr int TT = 58;
constexpr int NTB = 18;               // 18*58 = 1044 >= 1024

// ---- d_ws layout (bytes) ----
constexpr int WFB_OFF = 0;            // 144 x 288 bf16 (stage1+A1, dh-major K)
constexpr int WFC_OFF = 82944;        // 48 x 1440 bf16 (stage2+A2, K = dh*160+off)
constexpr int WFD_OFF = 221184;       // 16 x 320 bf16 (conv1d_1*bn, K = d*64+ci)
constexpr int BIASB_OFF = 231424;     // 144 f32
constexpr int BIASC_OFF = 232000;     // 48 f32
constexpr int BIASD_OFF = 232192;     // 16 f32

// ---- LDS layout (bytes) ----
constexpr int F2IN_OFF = 0;                      // 72 rows x 320 (160 bf16, 144 real)
constexpr int F3_OFF   = F2IN_OFF + 72 * 320;    // 23040: 68 rows x 144 (64 bf16, 48 real)
constexpr int SLAB_OFF = F3_OFF + 68 * 144;      // 32832: 88 rows x 80 (40 bf16, 27 real)
constexpr int H1_OFF   = SLAB_OFF;               // overlay: 60 rows x 68B (17 f32, 16 real)
constexpr int SMEM_BYTES = SLAB_OFF + 88 * 80;   // 39872 -> 4 blocks/CU
static_assert(SMEM_BYTES <= 40960, "4 blocks/CU");

typedef __attribute__((ext_vector_type(8))) short short8v;
typedef __attribute__((ext_vector_type(4))) float f32x4;

__device__ inline unsigned short f2b(float f) {
  union { float f; unsigned u; } v; v.f = f;
  unsigned r = (v.u + 0x7FFFu + ((v.u >> 16) & 1u)) >> 16;
  return (unsigned short)r;
}
// f2in swizzle: physical 16B-slot = logical slot ^ ((row>>2)&3). 20 slots/row,
// XOR of low 2 bits is bijective on 0..19.
__device__ inline int f2in_byte(int row, int slot, int within) {
  return F2IN_OFF + row * 320 + ((slot ^ ((row >> 2) & 3)) << 4) + within;
}
}

// ================= prep: fold einsums/BN into conv weight tables ===========
__global__ void prep_kernel(const float* __restrict__ A1, const float* __restrict__ A2,
                            const float* __restrict__ W1, const float* __restrict__ b1,
                            const float* __restrict__ W2, const float* __restrict__ b2,
                            const float* __restrict__ Wc1, const float* __restrict__ bc1,
                            const float* __restrict__ bn1w, const float* __restrict__ bn1b,
                            const float* __restrict__ bn1m, const float* __restrict__ bn1v,
                            unsigned char* __restrict__ ws) {
  unsigned short* wfB = (unsigned short*)(ws + WFB_OFF);
  unsigned short* wfC = (unsigned short*)(ws + WFC_OFF);
  unsigned short* wfD = (unsigned short*)(ws + WFD_OFF);
  float* biasB = (float*)(ws + BIASB_OFF);
  float* biasC = (float*)(ws + BIASC_OFF);
  float* biasD = (float*)(ws + BIASD_OFF);
  const int NWFB = 144 * 288;           // 41472
  const int NWFC = 48 * 1440;           // 69120
  const int NWFD = 16 * 320;            // 5120
  const int total = NWFB + NWFC + NWFD + 208;
  for (int idx = blockIdx.x * 256 + threadIdx.x; idx < total; idx += gridDim.x * 256) {
    if (idx < NWFB) {                      // wfB[ncol][dh*32 + mm], mm = v*3+ci
      int ncol = idx / 288, k = idx - ncol * 288;
      int dh = k >> 5, mm = k & 31;
      float val = 0.f;
      if (mm < 27) {
        int v = mm / 3, ci = mm - v * 3;
        int p = ncol / 48, rr = ncol - p * 48, c = rr / 3, e = rr - c * 3;
        int w = p * 3 + e;
        for (int k5 = 0; k5 < 5; ++k5)
          val += W1[(k5 * 16 + c) * 27 + ci * 9 + dh] * A1[k5 * 81 + v * 9 + w];
      }
      wfB[idx] = f2b(val);
    } else if (idx < NWFB + NWFC) {        // wfC[nc][dh*160 + off], off = p*48+ci2
      int i2 = idx - NWFB;
      int nc = i2 / 1440, k = i2 - nc * 1440;
      int dh = k / 160, off = k - dh * 160;
      float val = 0.f;
      if (off < 144) {
        int p = off / 48, ci2 = off - p * 48;
        int c2 = nc / 3, w2 = nc - c2 * 3;
        for (int k2 = 0; k2 < 3; ++k2)
          val += W2[(k2 * 16 + c2) * 432 + ci2 * 9 + dh] * A2[k2 * 9 + p * 3 + w2];
      }
      wfC[i2] = f2b(val);
    } else if (idx < NWFB + NWFC + NWFD) { // wfD[o3][d*64 + ci]
      int i3 = idx - (NWFB + NWFC);
      int o3 = i3 / 320, k = i3 - o3 * 320;
      int d = k >> 6, ci = k & 63;
      float val = 0.f;
      if (ci < 48) {
        float s1 = bn1w[o3] * rsqrtf(bn1v[o3] + 1e-5f);
        val = Wc1[o3 * 240 + ci * 5 + d] * s1;
      }
      wfD[i3] = f2b(val);
    } else {
      int ib = idx - (NWFB + NWFC + NWFD);
      if (ib < 144) {
        int p = ib / 48, rr = ib - p * 48, c = rr / 3, e = rr - c * 3;
        int w = p * 3 + e;
        float val = 0.f;
        for (int k5 = 0; k5 < 5; ++k5)
          for (int v = 0; v < 9; ++v)
            val += b1[k5 * 16 + c] * A1[k5 * 81 + v * 9 + w];
        biasB[ib] = val;
      } else if (ib < 192) {
        int nc = ib - 144, c2 = nc / 3, w2 = nc - c2 * 3;
        float val = 0.f;
        for (int k2 = 0; k2 < 3; ++k2)
          for (int p = 0; p < 3; ++p)
            val += b2[k2 * 16 + c2] * A2[k2 * 9 + p * 3 + w2];
        biasC[nc] = val;
      } else {
        int o3 = ib - 192;
        float s1 = bn1w[o3] * rsqrtf(bn1v[o3] + 1e-5f);
        biasD[o3] = bc1[o3] * s1 + bn1b[o3] - bn1m[o3] * s1;
      }
    }
  }
}

// ================= main fused kernel =======================================
__global__ __launch_bounds__(256, 4) void aff_encoder_kernel(
    const float* __restrict__ poses,
    const float* __restrict__ Wc2, const float* __restrict__ bc2,
    const float* __restrict__ bn2w, const float* __restrict__ bn2b,
    const float* __restrict__ bn2m, const float* __restrict__ bn2v,
    const unsigned char* __restrict__ ws, float* __restrict__ out) {
  __shared__ __attribute__((aligned(16))) unsigned char smem[SMEM_BYTES];
  const unsigned short* wfB = (const unsigned short*)(ws + WFB_OFF);
  const unsigned short* wfC = (const unsigned short*)(ws + WFC_OFF);
  const unsigned short* wfD = (const unsigned short*)(ws + WFD_OFF);
  const float* biasB = (const float*)(ws + BIASB_OFF);
  const float* biasC = (const float*)(ws + BIASC_OFF);
  const float* biasD = (const float*)(ws + BIASD_OFF);

  const int tid = threadIdx.x;
  const int n = blockIdx.y;
  const int t0 = blockIdx.x * TT;
  const int w = tid >> 6;          // wave id 0..3
  const int l = tid & 63;          // lane
  const int lrow = l & 15;
  const int q = l >> 4;
  const int q8 = q * 8;

  // ---- Phase 1: stage pose slab (packed dword bf16x2) + zero pads ----
  {
    unsigned* slab32 = (unsigned*)(smem + SLAB_OFF);
    for (int it = tid; it < 88 * 20; it += 256) {   // 20 dwords/row
      int r = it / 20, mi = it - r * 20;
      int t = t0 - 11 + r;
      int m0 = mi * 2;
      float v0 = 0.f, v1 = 0.f;
      if (t >= 0 && t < T_) {
        const float* src = poses + ((long)n * T_ + t) * 27;
        if (m0 < 27) v0 = src[m0];
        if (m0 + 1 < 27) v1 = src[m0 + 1];
      }
      slab32[it] = (unsigned)f2b(v0) | ((unsigned)f2b(v1) << 16);
    }
    // f2in logical pad slots 18,19 (cols 144..159), all 72 rows, via swizzle
    for (int it = tid; it < 72 * 8; it += 256) {
      int r = it >> 3, u = it & 7;
      int s = 18 + (u >> 2);
      *(unsigned*)(smem + f2in_byte(r, s, (u & 3) * 4)) = 0;
    }
    // f3 pads: cols 48..63 rows 0..67; rows 64..67 cols 0..47
    for (int it = tid; it < 68 * 8 + 4 * 24; it += 256) {
      if (it < 68 * 8) {
        int r = it >> 3, u = it & 7;
        *(unsigned*)(smem + F3_OFF + r * 144 + 96 + u * 4) = 0;
      } else {
        int k2 = it - 68 * 8;
        int r = 64 + k2 / 24, u = k2 - (k2 / 24) * 24;
        *(unsigned*)(smem + F3_OFF + r * 144 + u * 4) = 0;
      }
    }
  }
  __syncthreads();

  // ---- GEMM B: stage1 conv + A1. M=80 (72 real), N=144, K=9x32 ----
  // part 1: mt = w (rows 16w..16w+15, all real)
  {
    const int mt = w;
    const int arow = mt * 16 + lrow;
#pragma unroll
    for (int ntg = 0; ntg < 3; ++ntg) {
      f32x4 acc[6];
#pragma unroll
      for (int i = 0; i < 6; ++i) acc[i] = {0.f, 0.f, 0.f, 0.f};
#pragma unroll
      for (int dh = 0; dh < 9; ++dh) {
        short8v a = *(const short8v*)(smem + SLAB_OFF + ((arow + dh) * 40 + q8) * 2);
#pragma unroll
        for (int j = 0; j < 3; ++j) {
          const int nt = ntg * 3 + j;
          short8v b = *(const short8v*)(wfB + (nt * 16 + lrow) * 288 + dh * 32 + q8);
          const int ai = j * 2 + (dh & 1);
          acc[ai] = __builtin_amdgcn_mfma_f32_16x16x32_bf16(a, b, acc[ai], 0, 0, 0);
        }
      }
#pragma unroll
      for (int j = 0; j < 3; ++j) {
        const int ncol = (ntg * 3 + j) * 16 + lrow;
        const float bias = biasB[ncol];
#pragma unroll
        for (int jj = 0; jj < 4; ++jj) {
          const int r = mt * 16 + q * 4 + jj;
          const int t = t0 - 7 + r;
          float v = (t >= 0 && t < T_) ? acc[j * 2][jj] + acc[j * 2 + 1][jj] + bias : 0.f;
          *(unsigned short*)(smem + f2in_byte(r, ncol >> 3, (ncol & 7) * 2)) = f2b(v);
        }
      }
    }
  }
  // part 2: mt = 4 (rows 64..79, real 64..71); wave w takes nt = w, w+4, w+8
  {
    const int arow = 64 + lrow;
#pragma unroll
    for (int i = 0; i < 3; ++i) {
      const int nt = w + i * 4;
      if (nt < 9) {
        f32x4 a0 = {0.f, 0.f, 0.f, 0.f}, a1 = {0.f, 0.f, 0.f, 0.f};
#pragma unroll
        for (int dh = 0; dh < 9; ++dh) {
          short8v a = *(const short8v*)(smem + SLAB_OFF + ((arow + dh) * 40 + q8) * 2);
          short8v b = *(const short8v*)(wfB + (nt * 16 + lrow) * 288 + dh * 32 + q8);
          if (dh & 1) a1 = __builtin_amdgcn_mfma_f32_16x16x32_bf16(a, b, a1, 0, 0, 0);
          else        a0 = __builtin_amdgcn_mfma_f32_16x16x32_bf16(a, b, a0, 0, 0, 0);
        }
        const int ncol = nt * 16 + lrow;
        const float bias = biasB[ncol];
#pragma unroll
        for (int jj = 0; jj < 4; ++jj) {
          const int r = 64 + q * 4 + jj;
          if (r < 72) {
            const int t = t0 - 7 + r;
            float v = (t >= 0 && t < T_) ? a0[jj] + a1[jj] + bias : 0.f;
            *(unsigned short*)(smem + f2in_byte(r, ncol >> 3, (ncol & 7) * 2)) = f2b(v);
          }
        }
      }
    }
  }
  __syncthreads();

  // ---- GEMM C: stage2 conv + A2. M=64 (all real), N=48, K=9x160 ----
  {
    const int mt = w;
    const int arow = mt * 16 + lrow;
    f32x4 acc[6];
#pragma unroll
    for (int i = 0; i < 6; ++i) acc[i] = {0.f, 0.f, 0.f, 0.f};
#pragma unroll
    for (int dh = 0; dh < 9; ++dh) {
      const int r2 = arow + dh;
#pragma unroll
      for (int kkl = 0; kkl < 5; ++kkl) {
        short8v a = *(const short8v*)(smem + f2in_byte(r2, 4 * kkl + q, 0));
#pragma unroll
        for (int j = 0; j < 3; ++j) {
          short8v b = *(const short8v*)(wfC + (j * 16 + lrow) * 1440 + dh * 160 + kkl * 32 + q8);
          const int ai = j * 2 + ((dh * 5 + kkl) & 1);
          acc[ai] = __builtin_amdgcn_mfma_f32_16x16x32_bf16(a, b, acc[ai], 0, 0, 0);
        }
      }
    }
#pragma unroll
    for (int j = 0; j < 3; ++j) {
      const int ncol2 = j * 16 + lrow;
      const float bias = biasC[ncol2];
#pragma unroll
      for (int jj = 0; jj < 4; ++jj) {
        const int rt3 = mt * 16 + q * 4 + jj;
        const int t = t0 - 3 + rt3;
        float v = (t >= 0 && t < T_) ? acc[j * 2][jj] + acc[j * 2 + 1][jj] + bias : 0.f;
        *(unsigned short*)(smem + F3_OFF + rt3 * 144 + ncol2 * 2) = f2b(v);
      }
    }
  }
  __syncthreads();

  // ---- GEMM D: conv1d(5)+BN+leaky. M=64 (60 real), N=16, K=5x64 ----
  {
    const int mt = w;
    const int arow = mt * 16 + lrow;
    f32x4 a0 = {0.f, 0.f, 0.f, 0.f}, a1 = {0.f, 0.f, 0.f, 0.f};
#pragma unroll
    for (int d = 0; d < 5; ++d) {
#pragma unroll
      for (int kkl = 0; kkl < 2; ++kkl) {
        short8v a = *(const short8v*)(smem + F3_OFF + (arow + d) * 144 + (kkl * 32 + q8) * 2);
        short8v b = *(const short8v*)(wfD + lrow * 320 + d * 64 + kkl * 32 + q8);
        if ((d * 2 + kkl) & 1) a1 = __builtin_amdgcn_mfma_f32_16x16x32_bf16(a, b, a1, 0, 0, 0);
        else                   a0 = __builtin_amdgcn_mfma_f32_16x16x32_bf16(a, b, a0, 0, 0, 0);
      }
    }
    const float bias = biasD[lrow];
#pragma unroll
    for (int jj = 0; jj < 4; ++jj) {
      const int rh = mt * 16 + q * 4 + jj;
      if (rh < 60) {
        const int t = t0 - 1 + rh;
        float v = 0.f;
        if (t >= 0 && t < T_) {
          float x = a0[jj] + a1[jj] + bias;
          v = x > 0.f ? x : 0.01f * x;
        }
        *(float*)(smem + H1_OFF + (rh * 17 + lrow) * 4) = v;
      }
    }
  }
  __syncthreads();

  // ---- Stage E: conv1d(3) + BN + leaky -> out[n][t][8] ----
  for (int it = tid; it < TT * 8; it += 256) {
    int rt = it >> 3, o4 = it & 7;
    int t = t0 + rt;
    if (t >= T_) continue;
    float s2 = bn2w[o4] * rsqrtf(bn2v[o4] + 1e-5f);
    float t2 = bc2[o4] * s2 + bn2b[o4] - bn2m[o4] * s2;
    float acc = 0.f;
#pragma unroll
    for (int d = 0; d < 3; ++d) {
      const float* hr = (const float*)(smem + H1_OFF + (rt + d) * 68);
#pragma unroll
      for (int ci = 0; ci < 16; ++ci)
        acc = fmaf(hr[ci], Wc2[(o4 * 16 + ci) * 3 + d], acc);
    }
    float v = acc * s2 + t2;
    out[((long)n * T_ + t) * 8 + o4] = v > 0.f ? v : 0.01f * v;
  }
}

extern "C" void kernel_launch(void* const* d_in, const int* in_sizes, int n_in,
                              void* d_out, int out_size, void* d_ws, size_t ws_size,
                              hipStream_t stream) {
  (void)in_sizes; (void)n_in; (void)out_size; (void)ws_size;
  const float* poses = (const float*)d_in[0];
  const float* A1    = (const float*)d_in[1];
  const float* A2    = (const float*)d_in[2];
  const float* W1    = (const float*)d_in[3];
  const float* b1    = (const float*)d_in[4];
  const float* W2    = (const float*)d_in[5];
  const float* b2    = (const float*)d_in[6];
  const float* Wc1   = (const float*)d_in[7];
  const float* bc1   = (const float*)d_in[8];
  const float* bn1w  = (const float*)d_in[9];
  const float* bn1b  = (const float*)d_in[10];
  const float* bn1m  = (const float*)d_in[11];
  const float* bn1v  = (const float*)d_in[12];
  const float* Wc2   = (const float*)d_in[13];
  const float* bc2   = (const float*)d_in[14];
  const float* bn2w  = (const float*)d_in[15];
  const float* bn2b  = (const float*)d_in[16];
  const float* bn2m  = (const float*)d_in[17];
  const float* bn2v  = (const float*)d_in[18];
  float* out = (float*)d_out;
  unsigned char* ws = (unsigned char*)d_ws;

  hipLaunchKernelGGL(prep_kernel, dim3(64), dim3(256), 0, stream,
                     A1, A2, W1, b1, W2, b2, Wc1, bc1, bn1w, bn1b, bn1m, bn1v, ws);
  hipLaunchKernelGGL(aff_encoder_kernel, dim3(NTB, NBATCH), dim3(256), 0, stream,
                     poses, Wc2, bc2, bn2w, bn2b, bn2m, bn2v, ws, out);
}

// Round 5
// 154.925 us; speedup vs baseline: 13.5731x; 2.1910x over previous
//
#include <hip/hip_runtime.h>

namespace {
constexpr int T_ = 1024;
constexpr int NBATCH = 256;
constexpr int TT = 50;
constexpr int NTB = 21;               // 21*50 = 1050 >= 1024

// ---- d_ws layout (bytes) ----
constexpr int WFB_OFF = 0;            // 144 x 288 bf16 (stage1+A1, dh-major K)
constexpr int WFC_OFF = 82944;        // 48 x 1440 bf16 (stage2+A2, K = dh*160+off)
constexpr int WFD_OFF = 221184;       // 16 x 320 bf16 (conv1d_1*bn, K = d*64+ci)
constexpr int BIASB_OFF = 231424;     // 144 f32
constexpr int BIASC_OFF = 232000;     // 48 f32
constexpr int BIASD_OFF = 232192;     // 16 f32

// ---- LDS layout (bytes) ----
constexpr int F2IN_OFF = 0;                      // 72 rows x 320 (160 bf16, 144 real; rows 0..63 written, 64..71 zero)
constexpr int F3_OFF   = F2IN_OFF + 72 * 320;    // 23040: 68 rows x 144 (64 bf16, 48 real)
constexpr int SLAB_OFF = F3_OFF + 68 * 144;      // 32832: 72 rows x 80 (40 bf16, 27 real)
constexpr int H1_OFF   = SLAB_OFF;               // overlay: 52 rows x 68B (17 f32, 16 real)
constexpr int SMEM_BYTES = SLAB_OFF + 72 * 80;   // 38592 -> 4 blocks/CU
static_assert(SMEM_BYTES <= 40960, "4 blocks/CU");

typedef __attribute__((ext_vector_type(8))) short short8v;
typedef __attribute__((ext_vector_type(4))) float f32x4;

__device__ inline unsigned short f2b(float f) {
  union { float f; unsigned u; } v; v.f = f;
  unsigned r = (v.u + 0x7FFFu + ((v.u >> 16) & 1u)) >> 16;
  return (unsigned short)r;
}
// f2in swizzle: physical 16B-slot = logical slot ^ ((row>>2)&3). 20 slots/row.
__device__ inline int f2in_byte(int row, int slot, int within) {
  return F2IN_OFF + row * 320 + ((slot ^ ((row >> 2) & 3)) << 4) + within;
}
}

// ================= prep: fold einsums/BN into conv weight tables ===========
__global__ void prep_kernel(const float* __restrict__ A1, const float* __restrict__ A2,
                            const float* __restrict__ W1, const float* __restrict__ b1,
                            const float* __restrict__ W2, const float* __restrict__ b2,
                            const float* __restrict__ Wc1, const float* __restrict__ bc1,
                            const float* __restrict__ bn1w, const float* __restrict__ bn1b,
                            const float* __restrict__ bn1m, const float* __restrict__ bn1v,
                            unsigned char* __restrict__ ws) {
  unsigned short* wfB = (unsigned short*)(ws + WFB_OFF);
  unsigned short* wfC = (unsigned short*)(ws + WFC_OFF);
  unsigned short* wfD = (unsigned short*)(ws + WFD_OFF);
  float* biasB = (float*)(ws + BIASB_OFF);
  float* biasC = (float*)(ws + BIASC_OFF);
  float* biasD = (float*)(ws + BIASD_OFF);
  const int NWFB = 144 * 288;           // 41472
  const int NWFC = 48 * 1440;           // 69120
  const int NWFD = 16 * 320;            // 5120
  const int total = NWFB + NWFC + NWFD + 208;
  for (int idx = blockIdx.x * 256 + threadIdx.x; idx < total; idx += gridDim.x * 256) {
    if (idx < NWFB) {                      // wfB[ncol][dh*32 + mm], mm = v*3+ci
      int ncol = idx / 288, k = idx - ncol * 288;
      int dh = k >> 5, mm = k & 31;
      float val = 0.f;
      if (mm < 27) {
        int v = mm / 3, ci = mm - v * 3;
        int p = ncol / 48, rr = ncol - p * 48, c = rr / 3, e = rr - c * 3;
        int w = p * 3 + e;
        for (int k5 = 0; k5 < 5; ++k5)
          val += W1[(k5 * 16 + c) * 27 + ci * 9 + dh] * A1[k5 * 81 + v * 9 + w];
      }
      wfB[idx] = f2b(val);
    } else if (idx < NWFB + NWFC) {        // wfC[nc][dh*160 + off], off = p*48+ci2
      int i2 = idx - NWFB;
      int nc = i2 / 1440, k = i2 - nc * 1440;
      int dh = k / 160, off = k - dh * 160;
      float val = 0.f;
      if (off < 144) {
        int p = off / 48, ci2 = off - p * 48;
        int c2 = nc / 3, w2 = nc - c2 * 3;
        for (int k2 = 0; k2 < 3; ++k2)
          val += W2[(k2 * 16 + c2) * 432 + ci2 * 9 + dh] * A2[k2 * 9 + p * 3 + w2];
      }
      wfC[i2] = f2b(val);
    } else if (idx < NWFB + NWFC + NWFD) { // wfD[o3][d*64 + ci]
      int i3 = idx - (NWFB + NWFC);
      int o3 = i3 / 320, k = i3 - o3 * 320;
      int d = k >> 6, ci = k & 63;
      float val = 0.f;
      if (ci < 48) {
        float s1 = bn1w[o3] * rsqrtf(bn1v[o3] + 1e-5f);
        val = Wc1[o3 * 240 + ci * 5 + d] * s1;
      }
      wfD[i3] = f2b(val);
    } else {
      int ib = idx - (NWFB + NWFC + NWFD);
      if (ib < 144) {
        int p = ib / 48, rr = ib - p * 48, c = rr / 3, e = rr - c * 3;
        int w = p * 3 + e;
        float val = 0.f;
        for (int k5 = 0; k5 < 5; ++k5)
          for (int v = 0; v < 9; ++v)
            val += b1[k5 * 16 + c] * A1[k5 * 81 + v * 9 + w];
        biasB[ib] = val;
      } else if (ib < 192) {
        int nc = ib - 144, c2 = nc / 3, w2 = nc - c2 * 3;
        float val = 0.f;
        for (int k2 = 0; k2 < 3; ++k2)
          for (int p = 0; p < 3; ++p)
            val += b2[k2 * 16 + c2] * A2[k2 * 9 + p * 3 + w2];
        biasC[nc] = val;
      } else {
        int o3 = ib - 192;
        float s1 = bn1w[o3] * rsqrtf(bn1v[o3] + 1e-5f);
        biasD[o3] = bc1[o3] * s1 + bn1b[o3] - bn1m[o3] * s1;
      }
    }
  }
}

// ================= main fused kernel =======================================
__global__ __launch_bounds__(256, 4) void aff_encoder_kernel(
    const float* __restrict__ poses,
    const float* __restrict__ Wc2, const float* __restrict__ bc2,
    const float* __restrict__ bn2w, const float* __restrict__ bn2b,
    const float* __restrict__ bn2m, const float* __restrict__ bn2v,
    const unsigned char* __restrict__ ws, float* __restrict__ out) {
  __shared__ __attribute__((aligned(16))) unsigned char smem[SMEM_BYTES];
  const unsigned short* wfB = (const unsigned short*)(ws + WFB_OFF);
  const unsigned short* wfC = (const unsigned short*)(ws + WFC_OFF);
  const unsigned short* wfD = (const unsigned short*)(ws + WFD_OFF);
  const float* biasB = (const float*)(ws + BIASB_OFF);
  const float* biasC = (const float*)(ws + BIASC_OFF);
  const float* biasD = (const float*)(ws + BIASD_OFF);

  const int tid = threadIdx.x;
  const int n = blockIdx.y;
  const int t0 = blockIdx.x * TT;
  const int w = tid >> 6;          // wave id 0..3
  const int l = tid & 63;          // lane
  const int lrow = l & 15;
  const int q = l >> 4;
  const int q8 = q * 8;

  // ---- Phase 1: stage pose slab (packed dword bf16x2) + zero pads ----
  {
    unsigned* slab32 = (unsigned*)(smem + SLAB_OFF);
    for (int it = tid; it < 72 * 20; it += 256) {   // 20 dwords/row
      int r = it / 20, mi = it - r * 20;
      int t = t0 - 11 + r;
      int m0 = mi * 2;
      float v0 = 0.f, v1 = 0.f;
      if (t >= 0 && t < T_) {
        const float* src = poses + ((long)n * T_ + t) * 27;
        if (m0 < 27) v0 = src[m0];
        if (m0 + 1 < 27) v1 = src[m0 + 1];
      }
      slab32[it] = (unsigned)f2b(v0) | ((unsigned)f2b(v1) << 16);
    }
    // f2in: pad slots 18,19 (cols 144..159) rows 0..63 via swizzle
    for (int it = tid; it < 64 * 8; it += 256) {
      int r = it >> 3, u = it & 7;
      int s = 18 + (u >> 2);
      *(unsigned*)(smem + f2in_byte(r, s, (u & 3) * 4)) = 0;
    }
    // f2in: full rows 64..71 zero (linear ok — swizzle permutes within row)
    for (int it = tid; it < 8 * 80; it += 256) {
      int r = 64 + it / 80, u = it - (it / 80) * 80;
      *(unsigned*)(smem + F2IN_OFF + r * 320 + u * 4) = 0;
    }
    // f3 pads: cols 48..63 rows 0..67; rows 56..67 cols 0..47
    for (int it = tid; it < 68 * 8 + 12 * 24; it += 256) {
      if (it < 68 * 8) {
        int r = it >> 3, u = it & 7;
        *(unsigned*)(smem + F3_OFF + r * 144 + 96 + u * 4) = 0;
      } else {
        int k2 = it - 68 * 8;
        int r = 56 + k2 / 24, u = k2 - (k2 / 24) * 24;
        *(unsigned*)(smem + F3_OFF + r * 144 + u * 4) = 0;
      }
    }
  }
  __syncthreads();

  // ---- GEMM B: stage1 conv + A1. M=64 (4 mt), N=144 (9 nt), K=9x32 ----
  // Wave nt-split {3,2,2,2}: b loaded once per nt, reused across all 4 mt.
  {
    const int ntS = (w == 0) ? 0 : (2 * w + 1);
    const int ntN = (w == 0) ? 3 : 2;
#pragma unroll
    for (int ni = 0; ni < 3; ++ni) {
      if (ni < ntN) {
        const int nt = ntS + ni;
        short8v b[9];
#pragma unroll
        for (int dh = 0; dh < 9; ++dh)
          b[dh] = *(const short8v*)(wfB + (nt * 16 + lrow) * 288 + dh * 32 + q8);
        const int ncol = nt * 16 + lrow;
        const float bias = biasB[ncol];
#pragma unroll
        for (int mt = 0; mt < 4; ++mt) {
          short8v a[9];
#pragma unroll
          for (int dh = 0; dh < 9; ++dh)
            a[dh] = *(const short8v*)(smem + SLAB_OFF + ((mt * 16 + lrow + dh) * 40 + q8) * 2);
          f32x4 c0 = {0.f, 0.f, 0.f, 0.f}, c1 = {0.f, 0.f, 0.f, 0.f};
#pragma unroll
          for (int dh = 0; dh < 9; ++dh) {
            if (dh & 1) c1 = __builtin_amdgcn_mfma_f32_16x16x32_bf16(a[dh], b[dh], c1, 0, 0, 0);
            else        c0 = __builtin_amdgcn_mfma_f32_16x16x32_bf16(a[dh], b[dh], c0, 0, 0, 0);
          }
#pragma unroll
          for (int jj = 0; jj < 4; ++jj) {
            const int r = mt * 16 + q * 4 + jj;
            const int t = t0 - 7 + r;
            float v = (t >= 0 && t < T_) ? c0[jj] + c1[jj] + bias : 0.f;
            *(unsigned short*)(smem + f2in_byte(r, ncol >> 3, (ncol & 7) * 2)) = f2b(v);
          }
        }
      }
    }
  }
  __syncthreads();

  // ---- GEMM C: stage2 conv + A2. M=64 (4 mt), N=48 (3 nt), K=45 frags ----
  // Waves 0..2 each own one nt; b batched per 9-frag group, reused over 4 mt.
  if (w < 3) {
    const int nt = w;
    const int ncol2 = nt * 16 + lrow;
    const float bias = biasC[ncol2];
    f32x4 acc[4];
#pragma unroll
    for (int mt = 0; mt < 4; ++mt) acc[mt] = {0.f, 0.f, 0.f, 0.f};
#pragma unroll
    for (int g = 0; g < 5; ++g) {          // kf = g*9 + i, kf -> (dh=kf/5, kkl=kf%5)
      short8v b[9];
#pragma unroll
      for (int i = 0; i < 9; ++i) {
        const int kf = g * 9 + i, dh = kf / 5, kkl = kf % 5;
        b[i] = *(const short8v*)(wfC + ncol2 * 1440 + dh * 160 + kkl * 32 + q8);
      }
#pragma unroll
      for (int mt = 0; mt < 4; ++mt) {
        short8v a[9];
#pragma unroll
        for (int i = 0; i < 9; ++i) {
          const int kf = g * 9 + i, dh = kf / 5, kkl = kf % 5;
          a[i] = *(const short8v*)(smem + f2in_byte(mt * 16 + lrow + dh, 4 * kkl + q, 0));
        }
#pragma unroll
        for (int i = 0; i < 9; ++i)
          acc[mt] = __builtin_amdgcn_mfma_f32_16x16x32_bf16(a[i], b[i], acc[mt], 0, 0, 0);
      }
    }
#pragma unroll
    for (int mt = 0; mt < 4; ++mt) {
#pragma unroll
      for (int jj = 0; jj < 4; ++jj) {
        const int rt3 = mt * 16 + q * 4 + jj;
        if (rt3 < 56) {
          const int t = t0 - 3 + rt3;
          float v = (t >= 0 && t < T_) ? acc[mt][jj] + bias : 0.f;
          *(unsigned short*)(smem + F3_OFF + rt3 * 144 + ncol2 * 2) = f2b(v);
        }
      }
    }
  }
  __syncthreads();

  // ---- GEMM D: conv1d(5)+BN+leaky. M=64 (wave=mt), N=16, K=10 frags ----
  {
    const int arow = w * 16 + lrow;
    short8v a[10], b[10];
#pragma unroll
    for (int kf = 0; kf < 10; ++kf) {
      const int d = kf >> 1, kkl = kf & 1;
      b[kf] = *(const short8v*)(wfD + lrow * 320 + d * 64 + kkl * 32 + q8);
      a[kf] = *(const short8v*)(smem + F3_OFF + (arow + d) * 144 + (kkl * 32 + q8) * 2);
    }
    f32x4 c0 = {0.f, 0.f, 0.f, 0.f}, c1 = {0.f, 0.f, 0.f, 0.f};
#pragma unroll
    for (int kf = 0; kf < 10; ++kf) {
      if (kf & 1) c1 = __builtin_amdgcn_mfma_f32_16x16x32_bf16(a[kf], b[kf], c1, 0, 0, 0);
      else        c0 = __builtin_amdgcn_mfma_f32_16x16x32_bf16(a[kf], b[kf], c0, 0, 0, 0);
    }
    const float bias = biasD[lrow];
#pragma unroll
    for (int jj = 0; jj < 4; ++jj) {
      const int rh = w * 16 + q * 4 + jj;
      if (rh < 52) {
        const int t = t0 - 1 + rh;
        float v = 0.f;
        if (t >= 0 && t < T_) {
          float x = c0[jj] + c1[jj] + bias;
          v = x > 0.f ? x : 0.01f * x;
        }
        *(float*)(smem + H1_OFF + (rh * 17 + lrow) * 4) = v;
      }
    }
  }
  __syncthreads();

  // ---- Stage E: conv1d(3) + BN + leaky -> out[n][t][8] ----
  for (int it = tid; it < TT * 8; it += 256) {
    int rt = it >> 3, o4 = it & 7;
    int t = t0 + rt;
    if (t >= T_) continue;
    float s2 = bn2w[o4] * rsqrtf(bn2v[o4] + 1e-5f);
    float t2 = bc2[o4] * s2 + bn2b[o4] - bn2m[o4] * s2;
    float acc = 0.f;
#pragma unroll
    for (int d = 0; d < 3; ++d) {
      const float* hr = (const float*)(smem + H1_OFF + (rt + d) * 68);
#pragma unroll
      for (int ci = 0; ci < 16; ++ci)
        acc = fmaf(hr[ci], Wc2[(o4 * 16 + ci) * 3 + d], acc);
    }
    float v = acc * s2 + t2;
    out[((long)n * T_ + t) * 8 + o4] = v > 0.f ? v : 0.01f * v;
  }
}

extern "C" void kernel_launch(void* const* d_in, const int* in_sizes, int n_in,
                              void* d_out, int out_size, void* d_ws, size_t ws_size,
                              hipStream_t stream) {
  (void)in_sizes; (void)n_in; (void)out_size; (void)ws_size;
  const float* poses = (const float*)d_in[0];
  const float* A1    = (const float*)d_in[1];
  const float* A2    = (const float*)d_in[2];
  const float* W1    = (const float*)d_in[3];
  const float* b1    = (const float*)d_in[4];
  const float* W2    = (const float*)d_in[5];
  const float* b2    = (const float*)d_in[6];
  const float* Wc1   = (const float*)d_in[7];
  const float* bc1   = (const float*)d_in[8];
  const float* bn1w  = (const float*)d_in[9];
  const float* bn1b  = (const float*)d_in[10];
  const float* bn1m  = (const float*)d_in[11];
  const float* bn1v  = (const float*)d_in[12];
  const float* Wc2   = (const float*)d_in[13];
  const float* bc2   = (const float*)d_in[14];
  const float* bn2w  = (const float*)d_in[15];
  const float* bn2b  = (const float*)d_in[16];
  const float* bn2m  = (const float*)d_in[17];
  const float* bn2v  = (const float*)d_in[18];
  float* out = (float*)d_out;
  unsigned char* ws = (unsigned char*)d_ws;

  hipLaunchKernelGGL(prep_kernel, dim3(64), dim3(256), 0, stream,
                     A1, A2, W1, b1, W2, b2, Wc1, bc1, bn1w, bn1b, bn1m, bn1v, ws);
  hipLaunchKernelGGL(aff_encoder_kernel, dim3(NTB, NBATCH), dim3(256), 0, stream,
                     poses, Wc2, bc2, bn2w, bn2b, bn2m, bn2v, ws, out);
}